// Round 18
// baseline (202.937 us; speedup 1.0000x reference)
//
#include <hip/hip_runtime.h>
#include <stdint.h>

#define T_LEN 1460
#define CSZ 20                     // steps per chunk; 1460 = 73 * 20
#define NCHK 73
#define STEPB 592                  // A 256 | pad 16 | B 256 | V 64
#define ABASE 0
#define BBASE 272
#define VBASE 528
#define CHB (CSZ * STEPB)          // 11840
// pring ring-4: chunk c in slot c&3; written region c-1 (producers, from regs
// loaded region c-2), read regions c (w1 ss: A.xy,V.xy), c+1 (w0 su: A.zw,V.z),
// c+2 (w1 linear: B); slot reused by chunk c+4 written region c+3 > c+2. OK.

__device__ __forceinline__ float sigmf(float x) {
    float e = __builtin_amdgcn_exp2f(-1.44269504f * x);
    return __builtin_amdgcn_rcpf(1.0f + e);
}
__device__ __forceinline__ float rcpf(float x) { return __builtin_amdgcn_rcpf(x); }
__device__ __forceinline__ float lanef(float x, int l) {
    return __int_as_float(__builtin_amdgcn_readlane(__float_as_int(x), l));
}

// sum over a 16-lane row via full-rate DPP adds; result broadcast to the row
__device__ __forceinline__ float row_sum16(float x) {
    x += __int_as_float(__builtin_amdgcn_update_dpp(0, __float_as_int(x), 0xB1, 0xF, 0xF, true));
    x += __int_as_float(__builtin_amdgcn_update_dpp(0, __float_as_int(x), 0x4E, 0xF, 0xF, true));
    x += __int_as_float(__builtin_amdgcn_update_dpp(0, __float_as_int(x), 0x141, 0xF, 0xF, true));
    x += __int_as_float(__builtin_amdgcn_update_dpp(0, __float_as_int(x), 0x140, 0xF, 0xF, true));
    return x;
}

// ---------------------------------------------------------------------------
// Fused kernel: 256 blocks (1 basin) x 4 waves.
//   w2,w3: producers — reg-double-buffered: region r issues chunk r+2 global
//          loads, then sigmoid-maps + writes chunk r+1 from regs (HBM latency
//          gets a full region to land — r17's critical-path leak removed).
//   w1   : ss-chain (chunk r) -> {qfr,qin}; linear reservoirs (chunk r-2) + out
//   w0   : su-chain (chunk r-1) — irreducible serial core.
// Sync: one __syncthreads per region (barrier drain = entire ledger).
// ---------------------------------------------------------------------------
__global__ __launch_bounds__(256, 1) void shm_fused_kernel(
    const float* __restrict__ xc,   // [B, T, 3]
    const float* __restrict__ lo,   // [B, T, 8, 16]
    float* __restrict__ out)        // [B, T]
{
    __shared__ __align__(16) char pring[4 * CHB];   // 47360 B
    __shared__ float qin[2][CSZ][16];   // ss->su  (chunk c slot c&1: w r=c, r r=c+1)
    __shared__ float qfr[2][CSZ][16];   // ss->lin (w r=c, r r=c+2; same-wave read-first)
    __shared__ float quo[2][CSZ][16];   // su->lin (w r=c+1, r r=c+2)

    const int lane = threadIdx.x & 63;
    const int wid  = threadIdx.x >> 6;
    const int m    = lane & 15;
    const float* xrow = xc + (size_t)blockIdx.x * T_LEN * 3;
    const float* lrow = lo + (size_t)blockIdx.x * T_LEN * 128;
    float* op = out + (size_t)blockIdx.x * T_LEN;

    float ss = 0.f, su = 5.f, sf = 1.f, si = 10.f, sb = 15.f, qk = 0.f;

    // producer lane constants
    const int ip = lane >> 3;
    const int mm = (2 * lane) & 15;
    const float Ac = (ip==1)?10.f:(ip==2)?20.f:(ip==3)?1.f:
                     (ip==5)?1.f:(ip==6)?1.f:(ip==7)?10.f:0.f;
    const float Bc = (ip==0)?10.f:(ip==1)?50.f:(ip==2)?680.f:(ip==3)?5.f:
                     (ip==4)?1.f:(ip==5)?19.f:(ip==6)?99.f:990.f;
    const bool dorcp = (ip >= 5);
    const bool dosm  = (ip == 0);
    const int wroff = (ip < 4 ? ABASE : BBASE) + mm * 16 + (ip & 3) * 4;
    const int pw = wid - 2;              // producer index 0,1 (10 steps each)

    // producer register double-buffer (all indices compile-time via unroll)
    float2 Xraw[10], Yraw[10];
    float  Xxv[10],  Yxv[10];

#define PLOAD(S, c) {                                                         \
    const int t0_ = (c) * CSZ;                                                \
    _Pragma("unroll") for (int i = 0; i < 10; ++i) {                          \
        const int tl = pw + 2 * i;                                            \
        S##raw[i] = *(const float2*)(lrow + (size_t)(t0_ + tl) * 128 + 2 * lane); \
        S##xv[i]  = (lane < 3) ? xrow[(size_t)(t0_ + tl) * 3 + lane] : 0.f;   \
    } }

#define PWRITE(S, c) {                                                        \
    char* sb_ = pring + ((c) & 3) * CHB;                                      \
    _Pragma("unroll") for (int i = 0; i < 10; ++i) {                          \
        const int tl = pw + 2 * i;                                            \
        const float temp = lanef(S##xv[i], 2);                                \
        const float tpos = fmaxf(temp, 0.f);                                  \
        float v0 = fmaf(sigmf(S##raw[i].x), Bc, Ac);                          \
        float v1 = fmaf(sigmf(S##raw[i].y), Bc, Ac);                          \
        if (dorcp) { v0 = rcpf(v0); v1 = rcpf(v1); }                          \
        if (dosm)  { v0 *= tpos;    v1 *= tpos; }                             \
        *(float*)(sb_ + tl * STEPB + wroff)      = v0;                        \
        *(float*)(sb_ + tl * STEPB + wroff + 16) = v1;                        \
        if (lane < 16) {                                                      \
            const float prec = lanef(S##xv[i], 0), pet = lanef(S##xv[i], 1);  \
            const int comp = lane & 3;                                        \
            const float vv = (comp == 0) ? (temp < 0.f ? prec : 0.f)          \
                           : (comp == 1) ? (temp < 0.f ? 0.f : prec)          \
                           : (comp == 2) ? 0.9f * pet : 0.f;                  \
            *(float*)(sb_ + tl * STEPB + VBASE + lane * 4) = vv;              \
        }                                                                     \
    } }

#define FOR20(X) X(0) X(1) X(2) X(3) X(4) X(5) X(6) X(7) X(8) X(9) \
                 X(10) X(11) X(12) X(13) X(14) X(15) X(16) X(17) X(18) X(19)

#define LINLOAD(J)                                                            \
    float4 LB##J = make_float4(0.f,0.f,0.f,0.f); float LF##J = 0.f, LO##J = 0.f; \
    if (doLin) {                                                              \
        LB##J = *(const float4*)(sbl + (J) * STEPB + BBASE + m * 16);         \
        LF##J = qfr[hl][J][m];                                                \
        LO##J = quo[hl][J][m];                                                \
    }

#define SSSTEP(J) {                                                           \
    float4 A_ = *(const float4*)(sbs + (J) * STEPB + m * 16);                 \
    float4 V_ = *(const float4*)(sbs + (J) * STEPB + VBASE + (m & ~3) * 4);   \
    const float qs_out = fminf(ss, A_.x);                                     \
    ss = (ss - qs_out) + V_.x;                                                \
    const float qsp = qs_out + V_.y;                                          \
    qfr[hs][J][m] = fmaxf(0.f, qsp - A_.y);                                   \
    qin[hs][J][m] = fminf(qsp, A_.y); }

#define LINSTEP(J, tt) {                                                      \
    sf += LF##J; const float qf_out = sf * LB##J.y; sf -= qf_out;             \
    const float qi_in = LO##J * LB##J.x;                                      \
    si += qi_in; const float qi_out = si * LB##J.z; si -= qi_out;             \
    sb += (LO##J - qi_in); const float qb_out = sb * LB##J.w; sb -= qb_out;   \
    const float q_ = row_sum16(qf_out + qi_out + qb_out) * 0.0625f;           \
    qk = (m == ((tt) & 15)) ? q_ : qk;                                        \
    if (((tt) & 15) == 15) op[((tt) & ~15) + m] = qk; }

#define SUSTEP(J) {                                                           \
    float4 A_ = *(const float4*)(sbu + (J) * STEPB + m * 16);                 \
    float4 V_ = *(const float4*)(sbu + (J) * STEPB + VBASE + (m & ~3) * 4);   \
    const float sumax = A_.z, beta = A_.w, et09 = V_.z;                       \
    const float inv = rcpf(sumax);                                            \
    const float pwp = 0.8f * sumax;                                           \
    const float e_i = et09 * inv;                                             \
    const float qu_in = qin[hu][J][m];                                        \
    const float u = su * inv;                                                 \
    const float psi = __builtin_amdgcn_exp2f(beta * __builtin_amdgcn_logf(u));\
    const float su_t = fmaf(qu_in, 1.f - psi, su);                            \
    const float su2 = fminf(su_t, sumax);                                     \
    const float ovf = fmaxf(0.f, su_t - sumax);                               \
    const float qu_out = fmaf(qu_in, psi, ovf);                               \
    const float ret = (su2 <= pwp) ? su2 * e_i : et09;                        \
    su = fmaxf(0.f, su2 - ret);                                               \
    quo[hu][J][m] = qu_out; }

// region r: producers load chunk r+2 -> LS, write chunk r+1 from WS;
// w1: linload chunk r-2, ss chunk r, linstep chunk r-2; w0: su chunk r-1.
#define REGION(r, WS, LS) {                                                   \
    if (wid >= 2) {                                                           \
        if ((r) <= 70) PLOAD(LS, (r) + 2)                                     \
        if ((r) <= 71) PWRITE(WS, (r) + 1)                                    \
    } else if (wid == 1) {                                                    \
        if (lane < 16) {                                                      \
            const bool doLin = ((r) >= 2);                                    \
            const int cl = doLin ? ((r) - 2) : 0;                             \
            const int hl = cl & 1;                                            \
            const char* sbl = pring + (cl & 3) * CHB;                         \
            FOR20(LINLOAD)                                                    \
            if ((r) <= 72) {                                                  \
                const char* sbs = pring + ((r) & 3) * CHB;                    \
                const int hs = (r) & 1;                                       \
                FOR20(SSSTEP)                                                 \
            }                                                                 \
            if (doLin) {                                                      \
                const int t0 = cl * CSZ;                                      \
                LINSTEP(0,  t0)      LINSTEP(1,  t0 + 1)  LINSTEP(2,  t0 + 2) \
                LINSTEP(3,  t0 + 3)  LINSTEP(4,  t0 + 4)  LINSTEP(5,  t0 + 5) \
                LINSTEP(6,  t0 + 6)  LINSTEP(7,  t0 + 7)  LINSTEP(8,  t0 + 8) \
                LINSTEP(9,  t0 + 9)  LINSTEP(10, t0 + 10) LINSTEP(11, t0 + 11)\
                LINSTEP(12, t0 + 12) LINSTEP(13, t0 + 13) LINSTEP(14, t0 + 14)\
                LINSTEP(15, t0 + 15) LINSTEP(16, t0 + 16) LINSTEP(17, t0 + 17)\
                LINSTEP(18, t0 + 18) LINSTEP(19, t0 + 19)                     \
            }                                                                 \
        }                                                                     \
    } else {                                                                  \
        if ((r) >= 1 && (r) <= 73 && lane < 16) {                             \
            const int cu = (r) - 1;                                           \
            const char* sbu = pring + (cu & 3) * CHB;                         \
            const int hu = cu & 1;                                            \
            FOR20(SUSTEP)                                                     \
        }                                                                     \
    }                                                                         \
    __syncthreads();                                                          \
}

    // prologue: producers load chunk 0 -> X, write chunk 0 (one-time exposed
    // latency), load chunk 1 -> Y
    if (wid >= 2) {
        PLOAD(X, 0)
        PWRITE(X, 0)
        PLOAD(Y, 1)
    }
    __syncthreads();

    // regions 0..74 (region r even: write from Y, load into X; odd: swap)
    for (int rr = 0; rr < 74; rr += 2) {
        REGION(rr,     Y, X)
        REGION(rr + 1, X, Y)
    }
    REGION(74, Y, X)

    // tail: lanes 0..3 of w1 hold q for t = 1456..1459
    if (wid == 1 && lane < 4) op[1456 + lane] = qk;

#undef PLOAD
#undef PWRITE
#undef FOR20
#undef LINLOAD
#undef SSSTEP
#undef LINSTEP
#undef SUSTEP
#undef REGION
}

extern "C" void kernel_launch(void* const* d_in, const int* in_sizes, int n_in,
                              void* d_out, int out_size, void* d_ws, size_t ws_size,
                              hipStream_t stream) {
    const float* xc = (const float*)d_in[0];   // [256,1460,3]
    const float* lo = (const float*)d_in[1];   // [256,1460,128]
    float* out = (float*)d_out;                // [256,1460,1]
    (void)d_ws; (void)ws_size;                 // no workspace needed

    shm_fused_kernel<<<dim3(256), dim3(256), 0, stream>>>(xc, lo, out);
}

// Round 20
// 186.985 us; speedup vs baseline: 1.0853x; 1.0853x over previous
//
#include <hip/hip_runtime.h>
#include <hip/hip_fp16.h>
#include <stdint.h>

#define T_LEN 1460
#define NBT (256 * T_LEN)          // 373,760 (b,t) records
#define NREC (NBT * 16)            // 5,980,160 chain records
#define CSZ 20                     // steps per chunk; 1460 = 73 * 20
#define PHB (CSZ * 1024)           // param half: 20 steps x 64 chains x 16B
#define VHB (CSZ * 64)             // V half: 20 steps x 4 basins x 16B
#define QHB (CSZ * 512)            // qin half: 20 steps x 64 chains x 8B

typedef __attribute__((address_space(3))) char lds_c;
typedef __attribute__((address_space(1))) const char g_c;

__device__ __forceinline__ float sigmf(float x) {
    float e = __builtin_amdgcn_exp2f(-1.44269504f * x);
    return __builtin_amdgcn_rcpf(1.0f + e);
}
__device__ __forceinline__ float rcpf(float x) { return __builtin_amdgcn_rcpf(x); }

__device__ __forceinline__ uint32_t pkh2(float a, float b) {
    __half2 h = __floats2half2_rn(a, b);
    union { __half2 h; uint32_t u; } c; c.h = h; return c.u;
}
__device__ __forceinline__ float2 h2f(uint32_t u) {
    union { uint32_t u; __half2 h; } c; c.u = u;
    return __half22float2(c.h);
}

// sum over each 16-lane row via full-rate DPP adds; result broadcast
__device__ __forceinline__ float row_sum16(float x) {
    x += __int_as_float(__builtin_amdgcn_update_dpp(0, __float_as_int(x), 0xB1, 0xF, 0xF, true));
    x += __int_as_float(__builtin_amdgcn_update_dpp(0, __float_as_int(x), 0x4E, 0xF, 0xF, true));
    x += __int_as_float(__builtin_amdgcn_update_dpp(0, __float_as_int(x), 0x141, 0xF, 0xF, true));
    x += __int_as_float(__builtin_amdgcn_update_dpp(0, __float_as_int(x), 0x140, 0xF, 0xF, true));
    return x;
}

// ---------------------------------------------------------------------------
// Kernel A: pointwise parameter mapping, f16-packed output.
// R2 per (b,t,m): uint4 = {sm,f_thr | sumax,beta | perc,rkf | rki,rkb} (16B).
// V per (b,t): float4 {sn, lpq, 0.9*pet, 0} (16B, single copy).
// ---------------------------------------------------------------------------
__global__ __launch_bounds__(256) void shm_param_kernel(
    const float* __restrict__ xc, const float* __restrict__ lo,
    uint4* __restrict__ R2, float* __restrict__ V)
{
    const int tid = blockIdx.x * 256 + threadIdx.x;
    const int m  = tid & 15;
    const int bt = tid >> 4;

    const float* lr = lo + (size_t)bt * 128 + m;
    const float r0 = lr[0],   r1 = lr[16],  r2 = lr[32],  r3 = lr[48];
    const float r4 = lr[64],  r5 = lr[80],  r6 = lr[96],  r7 = lr[112];

    const float* xp = xc + (size_t)bt * 3;
    const float prec = xp[0], pet = xp[1], temp = xp[2];
    const bool frozen = (temp < 0.f);
    const float tpos = frozen ? 0.f : temp;

    const float dd    = 10.f * sigmf(r0);
    const float sm    = tpos * dd;
    const float f_thr = fmaf(sigmf(r1), 50.f, 10.f);
    const float sumax = fmaf(sigmf(r2), 680.f, 20.f);
    const float beta  = fmaf(sigmf(r3), 5.f, 1.f);
    const float perc  = sigmf(r4);
    const float rkf   = rcpf(fmaf(sigmf(r5), 19.f, 1.f));
    const float rki   = rcpf(fmaf(sigmf(r6), 99.f, 1.f));
    const float rkb   = rcpf(fmaf(sigmf(r7), 990.f, 10.f));

    R2[tid] = make_uint4(pkh2(sm, f_thr), pkh2(sumax, beta),
                         pkh2(perc, rkf), pkh2(rki, rkb));
    if (m == 0)
        *(float4*)(V + (size_t)bt * 4) =
            make_float4(frozen ? prec : 0.f, frozen ? 0.f : prec, 0.9f * pet, 0.f);
}

// ---------------------------------------------------------------------------
// Kernel B: two-wave pipelined serial scan (r16 structure, f16 params).
// 64 blocks x 128 threads. wave0 = full nonlinear chain (ss, su); wave1 =
// DMA producer + linear reservoirs, one region behind, via qring.
// One __syncthreads per region = the entire ledger (barrier drains vmcnt).
// Per region: 22 DMA issues (20 R' + 2 V) vs 60 in the f32 version.
// ---------------------------------------------------------------------------
__global__ __launch_bounds__(128, 1) void shm_serial_kernel(
    const char* __restrict__ R2,
    const char* __restrict__ V,
    float* __restrict__ out)
{
    __shared__ __align__(16) char pring[2 * PHB];   // 40960 B
    __shared__ __align__(16) char vring[2 * VHB];   //  2560 B
    __shared__ __align__(16) char qring[2 * QHB];   // 20480 B

    const int lane = threadIdx.x & 63;
    const int wid  = threadIdx.x >> 6;
    const int m = lane & 15;
    const int bbase = blockIdx.x * 4;
    const int b = bbase + (lane >> 4);
    float* op = out + (size_t)b * T_LEN;

    lds_c* plp = (lds_c*)pring;
    lds_c* plv = (lds_c*)vring;

    // wave0 state
    float ss = 0.f, su = 5.f;
    // wave1 state
    float sf = 1.f, si = 10.f, sb = 15.f, qk = 0.f;

    // per-lane DMA source pointers (wave1 uses them)
    const char* pRd2 = R2 + (size_t)b * T_LEN * 256 + m * 16;  // +256B/step
    const char* pV1 = V + ((size_t)(bbase + (lane & 3)) * T_LEN + (lane >> 2)) * 16;
    const char* pV2 = V + ((size_t)(bbase + (lane & 3)) * T_LEN + 16 + (lane >> 2)) * 16;

#define FOR20(X) X(0) X(1) X(2) X(3) X(4) X(5) X(6) X(7) X(8) X(9) \
                 X(10) X(11) X(12) X(13) X(14) X(15) X(16) X(17) X(18) X(19)

// issue one chunk: 20 R' DMAs (1KB each: 64 chains x 16B) + 2 V DMAs
#define ISSUECHUNK(wbp, wbv) {                                                \
    _Pragma("unroll") for (int J = 0; J < 20; ++J) {                          \
        __builtin_amdgcn_global_load_lds((g_c*)pRd2, plp + (wbp) + J * 1024, 16, 0, 0); \
        pRd2 += 256;                                                          \
    }                                                                         \
    __builtin_amdgcn_global_load_lds((g_c*)pV1, plv + (wbv), 16, 0, 0);       \
    if (lane < 16)                                                            \
        __builtin_amdgcn_global_load_lds((g_c*)pV2, plv + (wbv) + 1024, 16, 0, 0); \
    pV1 += 320; pV2 += 320; }

// wave0: full nonlinear step (one ds_read_b128 -> all 8 params)
#define NSTEP(J) {                                                            \
    const uint4 U = *(const uint4*)(pring + php + (J) * 1024 + lane * 16);    \
    const float4 Vv = *(const float4*)(vring + phv + (J) * 64 + ((lane >> 4) << 4)); \
    const float2 p0 = h2f(U.x);   /* sm, f_thr */                             \
    const float2 p1 = h2f(U.y);   /* sumax, beta */                           \
    const float smv = p0.x, f_thr = p0.y, sumax = p1.x, beta = p1.y;          \
    const float sn = Vv.x, lpq = Vv.y, et09 = Vv.z;                           \
    const float inv = rcpf(sumax);                                            \
    const float pwp = 0.8f * sumax;                                           \
    const float e_i = et09 * inv;                                             \
    const float qs_out = fminf(ss, smv);                                      \
    ss = (ss - qs_out) + sn;                                                  \
    const float qsp = qs_out + lpq;                                           \
    const float qf_in = fmaxf(0.f, qsp - f_thr);                              \
    const float qu_in = fminf(qsp, f_thr);                                    \
    const float u = su * inv;                                                 \
    const float psi = __builtin_amdgcn_exp2f(beta * __builtin_amdgcn_logf(u));\
    const float su_t = fmaf(qu_in, 1.f - psi, su);                            \
    const float su2 = fminf(su_t, sumax);                                     \
    const float ovf = fmaxf(0.f, su_t - sumax);                               \
    const float qu_out = fmaf(qu_in, psi, ovf);                               \
    const float ret = (su2 <= pwp) ? su2 * e_i : et09;                        \
    su = fmaxf(0.f, su2 - ret);                                               \
    *(float2*)(qring + phq + (J) * 512 + lane * 8) = make_float2(qf_in, qu_out); }

// wave1: load linear inputs of chunk r-1
#define LLOAD(J)                                                              \
    float4 LB##J = make_float4(0.f, 0.f, 0.f, 0.f);                           \
    float LF##J = 0.f, LO##J = 0.f;                                           \
    if (doLin) {                                                              \
        const uint2 Ub = *(const uint2*)(pring + rbp + (J) * 1024 + lane * 16 + 8); \
        const float2 Qq = *(const float2*)(qring + rbq + (J) * 512 + lane * 8); \
        const float2 p2 = h2f(Ub.x);   /* perc, rkf */                        \
        const float2 p3 = h2f(Ub.y);   /* rki, rkb */                         \
        LB##J = make_float4(p2.x, p2.y, p3.x, p3.y);                          \
        LF##J = Qq.x; LO##J = Qq.y;                                           \
    }

#define LSTEP(J, tt) {                                                        \
    sf += LF##J; const float qf_out = sf * LB##J.y; sf -= qf_out;             \
    const float qi_in = LO##J * LB##J.x;                                      \
    si += qi_in; const float qi_out = si * LB##J.z; si -= qi_out;             \
    sb += (LO##J - qi_in); const float qb_out = sb * LB##J.w; sb -= qb_out;   \
    const float q_ = row_sum16(qf_out + qi_out + qb_out) * 0.0625f;           \
    qk = (m == ((tt) & 15)) ? q_ : qk;                                        \
    if (((tt) & 15) == 15) op[((tt) & ~15) + m] = qk; }

    // prologue: wave1 issues chunk 0 into half 0
    if (wid == 1) ISSUECHUNK(0, 0)
    __syncthreads();

    // region r: w0 computes chunk r (half r&1) -> qring[r&1];
    // w1 reads chunk r-1 (half 1-(r&1)) then issues chunk r+1 into that half.
    for (int r = 0; r <= 73; ++r) {
        const int h = r & 1;
        if (wid == 0) {
            if (r <= 72) {
                const uint32_t php = (uint32_t)h * PHB;
                const uint32_t phv = (uint32_t)h * VHB;
                const uint32_t phq = (uint32_t)h * QHB;
                FOR20(NSTEP)
            }
        } else {
            const uint32_t rbp = (uint32_t)(1 - h) * PHB;
            const uint32_t rbq = (uint32_t)(1 - h) * QHB;
            const bool doLin = (r >= 1);
            FOR20(LLOAD)
            if (r <= 71) ISSUECHUNK(rbp, (uint32_t)(1 - h) * VHB)
            if (doLin) {
                const int t0 = CSZ * (r - 1);
                LSTEP(0,  t0)      LSTEP(1,  t0 + 1)  LSTEP(2,  t0 + 2)
                LSTEP(3,  t0 + 3)  LSTEP(4,  t0 + 4)  LSTEP(5,  t0 + 5)
                LSTEP(6,  t0 + 6)  LSTEP(7,  t0 + 7)  LSTEP(8,  t0 + 8)
                LSTEP(9,  t0 + 9)  LSTEP(10, t0 + 10) LSTEP(11, t0 + 11)
                LSTEP(12, t0 + 12) LSTEP(13, t0 + 13) LSTEP(14, t0 + 14)
                LSTEP(15, t0 + 15) LSTEP(16, t0 + 16) LSTEP(17, t0 + 17)
                LSTEP(18, t0 + 18) LSTEP(19, t0 + 19)
            }
        }
        __syncthreads();
    }

    if (wid == 1 && m < 4) op[1456 + m] = qk;   // t = 1456..1459

#undef FOR20
#undef ISSUECHUNK
#undef NSTEP
#undef LLOAD
#undef LSTEP
}

// ---------------------------------------------------------------------------
// Fallback (proven round-2 kernel, f32, no workspace) if ws too small.
// ---------------------------------------------------------------------------
#define CS 10
#define NCHUNK 146
#define IST 66

__device__ __forceinline__ float lane0f(float x) {
    return __int_as_float(__builtin_amdgcn_readlane(__float_as_int(x), 0));
}

__global__ __launch_bounds__(256, 1) void shm_pc_kernel(
    const float* __restrict__ xc, const float* __restrict__ lo,
    float* __restrict__ out)
{
    __shared__ float pbuf[2][CS][8][IST];
    __shared__ float bbuf[2][CS][4][4];

    const int lane  = threadIdx.x & 63;
    const int wid   = threadIdx.x >> 6;
    const int bbase = blockIdx.x * 4;

    const int ip = lane >> 3;
    const float A  = (ip==1)?10.f : (ip==2)?20.f : (ip==3)?1.f :
                     (ip==5)?1.f  : (ip==6)?1.f  : (ip==7)?10.f : 0.f;
    const float Bc = (ip==0)?10.f : (ip==1)?50.f : (ip==2)?680.f : (ip==3)?5.f :
                     (ip==4)?1.f  : (ip==5)?19.f : (ip==6)?99.f  : 990.f;
    const bool drcp = (ip >= 5);
    const bool dsm  = (ip == 0);
    const int  mm   = (2*lane) & 15;

    auto produce = [&](int cc, int buf) {
        const int t0 = cc * CS;
        float2 raw[14];
        float xr0[14], xr1[14], xr2[14];
#pragma unroll
        for (int r = 0; r < 14; ++r) {
            const int tau = (wid - 1) + 3 * r;
            if (tau < 40) {
                const int g  = tau / CS;
                const int tl = tau - g * CS;
                const size_t rowoff = (size_t)(bbase + g) * T_LEN + (t0 + tl);
                raw[r] = *(const float2*)(lo + rowoff * 128 + 2 * lane);
                if (lane == 0) {
                    const float* xp = xc + rowoff * 3;
                    xr0[r] = xp[0]; xr1[r] = xp[1]; xr2[r] = xp[2];
                }
            }
        }
#pragma unroll
        for (int r = 0; r < 14; ++r) {
            const int tau = (wid - 1) + 3 * r;
            if (tau < 40) {
                const int g  = tau / CS;
                const int tl = tau - g * CS;
                const float prec = lane0f(xr0[r]);
                const float pet  = lane0f(xr1[r]);
                const float temp = lane0f(xr2[r]);
                const bool frozen = (temp < 0.f);
                const float tpos = frozen ? 0.f : temp;
                const float sn   = frozen ? prec : 0.f;
                const float lpq  = frozen ? 0.f : prec;
                const float et09 = 0.9f * pet;

                float v0 = fmaf(sigmf(raw[r].x), Bc, A);
                float v1 = fmaf(sigmf(raw[r].y), Bc, A);
                v0 = drcp ? rcpf(v0) : v0;
                v1 = drcp ? rcpf(v1) : v1;
                v0 = dsm ? v0 * tpos : v0;
                v1 = dsm ? v1 * tpos : v1;

                float* dst = &pbuf[buf][tl][ip][g * 16 + mm];
                *(float2*)dst = make_float2(v0, v1);
                if (lane == 0)
                    *(float4*)&bbuf[buf][tl][g][0] = make_float4(sn, lpq, et09, 0.f);
            }
        }
    };

    const int g = lane >> 4, m = lane & 15;
    float ss = 0.f, sf = 1.f, su = 5.f, si = 10.f, sb = 15.f;
    float* op = out + (size_t)(bbase + g) * T_LEN;

    if (wid != 0) produce(0, 0);
    __syncthreads();

    for (int c = 0; c < NCHUNK; ++c) {
        if (wid == 0) {
            const int buf = c & 1;
#pragma unroll
            for (int tl = 0; tl < CS; ++tl) {
                const float* rec = &pbuf[buf][tl][0][lane];
                const float sm    = rec[0 * IST];
                const float f_thr = rec[1 * IST];
                const float sumax = rec[2 * IST];
                const float beta  = rec[3 * IST];
                const float perc  = rec[4 * IST];
                const float rkf   = rec[5 * IST];
                const float rki   = rec[6 * IST];
                const float rkb   = rec[7 * IST];
                const float4 bx = *(const float4*)&bbuf[buf][tl][g][0];

                float qs_out = fminf(ss, sm);
                ss = ss - qs_out + bx.x;
                float qsp = qs_out + bx.y;
                float qf_in = fmaxf(0.f, qsp - f_thr);
                float qu_in = fminf(qsp, f_thr);
                sf += qf_in;
                float qf_out = sf * rkf;
                sf -= qf_out;
                float inv_sumax = rcpf(sumax);
                float u = su * inv_sumax;
                float psi = __builtin_amdgcn_exp2f(beta * __builtin_amdgcn_logf(u));
                float su_temp = fmaf(qu_in, 1.f - psi, su);
                su = fminf(su_temp, sumax);
                float ovf = fmaxf(0.f, su_temp - sumax);
                float qu_out = fmaf(qu_in, psi, ovf);
                float pwp = 0.8f * sumax;
                float ktheta = (su <= pwp) ? su * inv_sumax : 1.f;
                float ret = bx.z * ktheta;
                su = fmaxf(0.f, su - ret);
                float qi_in = qu_out * perc;
                si += qi_in;
                float qi_out = si * rki;
                si -= qi_out;
                float qb_in = qu_out - qi_in;
                sb += qb_in;
                float qb_out = sb * rkb;
                sb -= qb_out;

                float q = row_sum16(qf_out + qi_out + qb_out) * 0.0625f;
                if (m == 0) op[c * CS + tl] = q;
            }
        } else if (c + 1 < NCHUNK) {
            produce(c + 1, (c + 1) & 1);
        }
        __syncthreads();
    }
}

extern "C" void kernel_launch(void* const* d_in, const int* in_sizes, int n_in,
                              void* d_out, int out_size, void* d_ws, size_t ws_size,
                              hipStream_t stream) {
    const float* xc = (const float*)d_in[0];   // [256,1460,3]
    const float* lo = (const float*)d_in[1];   // [256,1460,128]
    float* out = (float*)d_out;                // [256,1460,1]

    const size_t R2_BYTES = (size_t)NREC * 16;  // 95,682,560
    const size_t V_BYTES  = (size_t)NBT * 16;   //  5,980,160

    if (ws_size >= R2_BYTES + V_BYTES) {
        uint4* R2 = (uint4*)d_ws;
        float* V  = (float*)((char*)d_ws + R2_BYTES);
        shm_param_kernel<<<dim3(NREC / 256), dim3(256), 0, stream>>>(xc, lo, R2, V);
        shm_serial_kernel<<<dim3(64), dim3(128), 0, stream>>>(
            (const char*)R2, (const char*)V, out);
    } else {
        shm_pc_kernel<<<dim3(64), dim3(256), 0, stream>>>(xc, lo, out);
    }
}

// Round 21
// 159.351 us; speedup vs baseline: 1.2735x; 1.1734x over previous
//
#include <hip/hip_runtime.h>
#include <hip/hip_fp16.h>
#include <stdint.h>

#define T_LEN 1460
#define NBT (256 * T_LEN)          // 373,760 (b,t) records
#define NREC (NBT * 16)            // 5,980,160 chain records
#define CSZ 20                     // steps per chunk; 1460 = 73 * 20
#define PCH (CSZ * 1024)           // param chunk: 20 x 64 chains x 16B = 20480
#define VCH (CSZ * 64)             // V chunk: 20 x 4 basins x 16B = 1280
#define Q1CH (CSZ * 512)           // {qf,qu} chunk: 20 x 64 x 8B = 10240
#define Q2CH (CSZ * 256)           // qu_out chunk: 20 x 64 x 4B = 5120

typedef __attribute__((address_space(3))) char lds_c;
typedef __attribute__((address_space(1))) const char g_c;

__device__ __forceinline__ float sigmf(float x) {
    float e = __builtin_amdgcn_exp2f(-1.44269504f * x);
    return __builtin_amdgcn_rcpf(1.0f + e);
}
__device__ __forceinline__ float rcpf(float x) { return __builtin_amdgcn_rcpf(x); }

__device__ __forceinline__ uint32_t pkh2(float a, float b) {
    __half2 h = __floats2half2_rn(a, b);
    union { __half2 h; uint32_t u; } c; c.h = h; return c.u;
}
__device__ __forceinline__ float2 h2f(uint32_t u) {
    union { uint32_t u; __half2 h; } c; c.u = u;
    return __half22float2(c.h);
}

// sum over each 16-lane row via full-rate DPP adds; result broadcast
__device__ __forceinline__ float row_sum16(float x) {
    x += __int_as_float(__builtin_amdgcn_update_dpp(0, __float_as_int(x), 0xB1, 0xF, 0xF, true));
    x += __int_as_float(__builtin_amdgcn_update_dpp(0, __float_as_int(x), 0x4E, 0xF, 0xF, true));
    x += __int_as_float(__builtin_amdgcn_update_dpp(0, __float_as_int(x), 0x141, 0xF, 0xF, true));
    x += __int_as_float(__builtin_amdgcn_update_dpp(0, __float_as_int(x), 0x140, 0xF, 0xF, true));
    return x;
}

// ---------------------------------------------------------------------------
// Kernel A (unchanged from r20, passed): f16-packed parameter mapping.
// ---------------------------------------------------------------------------
__global__ __launch_bounds__(256) void shm_param_kernel(
    const float* __restrict__ xc, const float* __restrict__ lo,
    uint4* __restrict__ R2, float* __restrict__ V)
{
    const int tid = blockIdx.x * 256 + threadIdx.x;
    const int m  = tid & 15;
    const int bt = tid >> 4;

    const float* lr = lo + (size_t)bt * 128 + m;
    const float r0 = lr[0],   r1 = lr[16],  r2 = lr[32],  r3 = lr[48];
    const float r4 = lr[64],  r5 = lr[80],  r6 = lr[96],  r7 = lr[112];

    const float* xp = xc + (size_t)bt * 3;
    const float prec = xp[0], pet = xp[1], temp = xp[2];
    const bool frozen = (temp < 0.f);
    const float tpos = frozen ? 0.f : temp;

    const float dd    = 10.f * sigmf(r0);
    const float sm    = tpos * dd;
    const float f_thr = fmaf(sigmf(r1), 50.f, 10.f);
    const float sumax = fmaf(sigmf(r2), 680.f, 20.f);
    const float beta  = fmaf(sigmf(r3), 5.f, 1.f);
    const float perc  = sigmf(r4);
    const float rkf   = rcpf(fmaf(sigmf(r5), 19.f, 1.f));
    const float rki   = rcpf(fmaf(sigmf(r6), 99.f, 1.f));
    const float rkb   = rcpf(fmaf(sigmf(r7), 990.f, 10.f));

    R2[tid] = make_uint4(pkh2(sm, f_thr), pkh2(sumax, beta),
                         pkh2(perc, rkf), pkh2(rki, rkb));
    if (m == 0)
        *(float4*)(V + (size_t)bt * 4) =
            make_float4(frozen ? prec : 0.f, frozen ? 0.f : prec, 0.9f * pet, 0.f);
}

// ---------------------------------------------------------------------------
// Kernel B: THREE-stage wave pipeline. 64 blocks x 192 threads.
//   w0: ss-chain chunk r  -> q1{qf,qu}; + all DMA issuing (chunk r+1)
//   w1: su-chain chunk r-1 (minimal issue load around the 60cy latency chain)
//   w2: linear reservoirs + 16-mean + store, chunk r-2
// Barrier-only sync. Intra-region slots fully disjoint:
//   pring ring-4: DMA->(r+1)&3, w0 reads r&3, w1 (r-1)&3, w2 (r-2)&3
//   vring/q1 ring-3 (residues r, r-1, r-2 mod 3 distinct), q2 ring-2.
// Lifetimes: chunk c last read region c+2; rewritten region c+3. OK.
// ---------------------------------------------------------------------------
__global__ __launch_bounds__(192, 1) void shm_serial_kernel(
    const char* __restrict__ R2,
    const char* __restrict__ V,
    float* __restrict__ out)
{
    __shared__ __align__(16) char pring[4 * PCH];    // 81920
    __shared__ __align__(16) char vring[3 * VCH];    //  3840
    __shared__ __align__(16) char q1[3 * Q1CH];      // 30720
    __shared__ __align__(16) char q2[2 * Q2CH];      // 10240

    const int lane = threadIdx.x & 63;
    const int wid  = threadIdx.x >> 6;
    const int m = lane & 15;
    const int bbase = blockIdx.x * 4;
    const int b = bbase + (lane >> 4);
    float* op = out + (size_t)b * T_LEN;

    lds_c* plp = (lds_c*)pring;
    lds_c* plv = (lds_c*)vring;
    const int voff = (lane >> 4) << 4;   // basin offset within V step-record

    // per-wave state
    float ss = 0.f;                       // w0
    float su = 5.f;                       // w1
    float sf = 1.f, si = 10.f, sb = 15.f, qk = 0.f;   // w2

    // DMA source pointers (w0)
    const char* pRd2 = R2 + (size_t)b * T_LEN * 256 + m * 16;
    const char* pV1 = V + ((size_t)(bbase + (lane & 3)) * T_LEN + (lane >> 2)) * 16;
    const char* pV2 = V + ((size_t)(bbase + (lane & 3)) * T_LEN + 16 + (lane >> 2)) * 16;

#define FOR20(X) X(0) X(1) X(2) X(3) X(4) X(5) X(6) X(7) X(8) X(9) \
                 X(10) X(11) X(12) X(13) X(14) X(15) X(16) X(17) X(18) X(19)

#define ISSUECHUNK(wbp, wbv) {                                                \
    _Pragma("unroll") for (int J = 0; J < 20; ++J) {                          \
        __builtin_amdgcn_global_load_lds((g_c*)pRd2, plp + (wbp) + J * 1024, 16, 0, 0); \
        pRd2 += 256;                                                          \
    }                                                                         \
    __builtin_amdgcn_global_load_lds((g_c*)pV1, plv + (wbv), 16, 0, 0);       \
    if (lane < 16)                                                            \
        __builtin_amdgcn_global_load_lds((g_c*)pV2, plv + (wbv) + 1024, 16, 0, 0); \
    pV1 += 320; pV2 += 320; }

// w0: ss-chain step (chunk r)
#define SSTEP(J) {                                                            \
    const uint32_t ux = *(const uint32_t*)(pring + sp0 + (J) * 1024 + lane * 16); \
    const float2 p0 = h2f(ux);            /* sm, f_thr */                     \
    const float2 snl = *(const float2*)(vring + sv0 + (J) * 64 + voff);       \
    const float qs_out = fminf(ss, p0.x);                                     \
    ss = (ss - qs_out) + snl.x;                                               \
    const float qsp = qs_out + snl.y;                                         \
    const float qf_ = fmaxf(0.f, qsp - p0.y);                                 \
    const float qu_ = fminf(qsp, p0.y);                                       \
    *(float2*)(q1 + sq10 + (J) * 512 + lane * 8) = make_float2(qf_, qu_); }

// w1: su-chain step (chunk r-1)
#define USTEP(J) {                                                            \
    const uint32_t uy = *(const uint32_t*)(pring + sp1 + (J) * 1024 + lane * 16 + 4); \
    const float2 p1 = h2f(uy);            /* sumax, beta */                   \
    const float et09 = *(const float*)(vring + sv1 + (J) * 64 + voff + 8);    \
    const float qu_in = *(const float*)(q1 + sq11 + (J) * 512 + lane * 8 + 4);\
    const float sumax = p1.x, beta = p1.y;                                    \
    const float inv = rcpf(sumax);                                            \
    const float pwp = 0.8f * sumax;                                           \
    const float e_i = et09 * inv;                                             \
    const float u = su * inv;                                                 \
    const float psi = __builtin_amdgcn_exp2f(beta * __builtin_amdgcn_logf(u));\
    const float su_t = fmaf(qu_in, 1.f - psi, su);                            \
    const float su2 = fminf(su_t, sumax);                                     \
    const float ovf = fmaxf(0.f, su_t - sumax);                               \
    const float qu_out = fmaf(qu_in, psi, ovf);                               \
    const float ret = (su2 <= pwp) ? su2 * e_i : et09;                        \
    su = fmaxf(0.f, su2 - ret);                                               \
    *(float*)(q2 + sq21 + (J) * 256 + lane * 4) = qu_out; }

// w2: linear step (chunk r-2)
#define LSTEP(J, tt) {                                                        \
    const uint2 ub = *(const uint2*)(pring + sp2 + (J) * 1024 + lane * 16 + 8); \
    const float2 p2 = h2f(ub.x);          /* perc, rkf */                     \
    const float2 p3 = h2f(ub.y);          /* rki, rkb */                      \
    const float qf_in = *(const float*)(q1 + sq12 + (J) * 512 + lane * 8);    \
    const float quo = *(const float*)(q2 + sq22 + (J) * 256 + lane * 4);      \
    sf += qf_in; const float qf_out = sf * p2.y; sf -= qf_out;                \
    const float qi_in = quo * p2.x;                                           \
    si += qi_in; const float qi_out = si * p3.x; si -= qi_out;                \
    sb += (quo - qi_in); const float qb_out = sb * p3.y; sb -= qb_out;        \
    const float q_ = row_sum16(qf_out + qi_out + qb_out) * 0.0625f;           \
    qk = (m == ((tt) & 15)) ? q_ : qk;                                        \
    if (((tt) & 15) == 15) op[((tt) & ~15) + m] = qk; }

    // prologue: w0 issues chunk 0 into slot 0
    if (wid == 0) ISSUECHUNK(0, 0)
    __syncthreads();

    for (int r = 0; r <= 74; ++r) {
        if (wid == 0) {
            if (r <= 71) ISSUECHUNK(((uint32_t)((r + 1) & 3)) * PCH,
                                    ((uint32_t)((r + 1) % 3)) * VCH)
            if (r <= 72) {
                const uint32_t sp0  = (uint32_t)(r & 3) * PCH;
                const uint32_t sv0  = (uint32_t)(r % 3) * VCH;
                const uint32_t sq10 = (uint32_t)(r % 3) * Q1CH;
                FOR20(SSTEP)
            }
        } else if (wid == 1) {
            if (r >= 1 && r <= 73) {
                const int cu = r - 1;
                const uint32_t sp1  = (uint32_t)(cu & 3) * PCH;
                const uint32_t sv1  = (uint32_t)(cu % 3) * VCH;
                const uint32_t sq11 = (uint32_t)(cu % 3) * Q1CH;
                const uint32_t sq21 = (uint32_t)(cu & 1) * Q2CH;
                FOR20(USTEP)
            }
        } else {
            if (r >= 2) {
                const int cl = r - 2;
                const uint32_t sp2  = (uint32_t)(cl & 3) * PCH;
                const uint32_t sq12 = (uint32_t)(cl % 3) * Q1CH;
                const uint32_t sq22 = (uint32_t)(cl & 1) * Q2CH;
                const int t0 = CSZ * cl;
                LSTEP(0,  t0)      LSTEP(1,  t0 + 1)  LSTEP(2,  t0 + 2)
                LSTEP(3,  t0 + 3)  LSTEP(4,  t0 + 4)  LSTEP(5,  t0 + 5)
                LSTEP(6,  t0 + 6)  LSTEP(7,  t0 + 7)  LSTEP(8,  t0 + 8)
                LSTEP(9,  t0 + 9)  LSTEP(10, t0 + 10) LSTEP(11, t0 + 11)
                LSTEP(12, t0 + 12) LSTEP(13, t0 + 13) LSTEP(14, t0 + 14)
                LSTEP(15, t0 + 15) LSTEP(16, t0 + 16) LSTEP(17, t0 + 17)
                LSTEP(18, t0 + 18) LSTEP(19, t0 + 19)
            }
        }
        __syncthreads();
    }

    if (wid == 2 && m < 4) op[1456 + m] = qk;   // t = 1456..1459

#undef FOR20
#undef ISSUECHUNK
#undef SSTEP
#undef USTEP
#undef LSTEP
}

// ---------------------------------------------------------------------------
// Fallback (proven round-2 kernel, f32, no workspace) if ws too small.
// ---------------------------------------------------------------------------
#define CS 10
#define NCHUNK 146
#define IST 66

__device__ __forceinline__ float lane0f(float x) {
    return __int_as_float(__builtin_amdgcn_readlane(__float_as_int(x), 0));
}

__global__ __launch_bounds__(256, 1) void shm_pc_kernel(
    const float* __restrict__ xc, const float* __restrict__ lo,
    float* __restrict__ out)
{
    __shared__ float pbuf[2][CS][8][IST];
    __shared__ float bbuf[2][CS][4][4];

    const int lane  = threadIdx.x & 63;
    const int wid   = threadIdx.x >> 6;
    const int bbase = blockIdx.x * 4;

    const int ip = lane >> 3;
    const float A  = (ip==1)?10.f : (ip==2)?20.f : (ip==3)?1.f :
                     (ip==5)?1.f  : (ip==6)?1.f  : (ip==7)?10.f : 0.f;
    const float Bc = (ip==0)?10.f : (ip==1)?50.f : (ip==2)?680.f : (ip==3)?5.f :
                     (ip==4)?1.f  : (ip==5)?19.f : (ip==6)?99.f  : 990.f;
    const bool drcp = (ip >= 5);
    const bool dsm  = (ip == 0);
    const int  mm   = (2*lane) & 15;

    auto produce = [&](int cc, int buf) {
        const int t0 = cc * CS;
        float2 raw[14];
        float xr0[14], xr1[14], xr2[14];
#pragma unroll
        for (int r = 0; r < 14; ++r) {
            const int tau = (wid - 1) + 3 * r;
            if (tau < 40) {
                const int g  = tau / CS;
                const int tl = tau - g * CS;
                const size_t rowoff = (size_t)(bbase + g) * T_LEN + (t0 + tl);
                raw[r] = *(const float2*)(lo + rowoff * 128 + 2 * lane);
                if (lane == 0) {
                    const float* xp = xc + rowoff * 3;
                    xr0[r] = xp[0]; xr1[r] = xp[1]; xr2[r] = xp[2];
                }
            }
        }
#pragma unroll
        for (int r = 0; r < 14; ++r) {
            const int tau = (wid - 1) + 3 * r;
            if (tau < 40) {
                const int g  = tau / CS;
                const int tl = tau - g * CS;
                const float prec = lane0f(xr0[r]);
                const float pet  = lane0f(xr1[r]);
                const float temp = lane0f(xr2[r]);
                const bool frozen = (temp < 0.f);
                const float tpos = frozen ? 0.f : temp;
                const float sn   = frozen ? prec : 0.f;
                const float lpq  = frozen ? 0.f : prec;
                const float et09 = 0.9f * pet;

                float v0 = fmaf(sigmf(raw[r].x), Bc, A);
                float v1 = fmaf(sigmf(raw[r].y), Bc, A);
                v0 = drcp ? rcpf(v0) : v0;
                v1 = drcp ? rcpf(v1) : v1;
                v0 = dsm ? v0 * tpos : v0;
                v1 = dsm ? v1 * tpos : v1;

                float* dst = &pbuf[buf][tl][ip][g * 16 + mm];
                *(float2*)dst = make_float2(v0, v1);
                if (lane == 0)
                    *(float4*)&bbuf[buf][tl][g][0] = make_float4(sn, lpq, et09, 0.f);
            }
        }
    };

    const int g = lane >> 4, m = lane & 15;
    float ss = 0.f, sf = 1.f, su = 5.f, si = 10.f, sb = 15.f;
    float* op = out + (size_t)(bbase + g) * T_LEN;

    if (wid != 0) produce(0, 0);
    __syncthreads();

    for (int c = 0; c < NCHUNK; ++c) {
        if (wid == 0) {
            const int buf = c & 1;
#pragma unroll
            for (int tl = 0; tl < CS; ++tl) {
                const float* rec = &pbuf[buf][tl][0][lane];
                const float sm    = rec[0 * IST];
                const float f_thr = rec[1 * IST];
                const float sumax = rec[2 * IST];
                const float beta  = rec[3 * IST];
                const float perc  = rec[4 * IST];
                const float rkf   = rec[5 * IST];
                const float rki   = rec[6 * IST];
                const float rkb   = rec[7 * IST];
                const float4 bx = *(const float4*)&bbuf[buf][tl][g][0];

                float qs_out = fminf(ss, sm);
                ss = ss - qs_out + bx.x;
                float qsp = qs_out + bx.y;
                float qf_in = fmaxf(0.f, qsp - f_thr);
                float qu_in = fminf(qsp, f_thr);
                sf += qf_in;
                float qf_out = sf * rkf;
                sf -= qf_out;
                float inv_sumax = rcpf(sumax);
                float u = su * inv_sumax;
                float psi = __builtin_amdgcn_exp2f(beta * __builtin_amdgcn_logf(u));
                float su_temp = fmaf(qu_in, 1.f - psi, su);
                su = fminf(su_temp, sumax);
                float ovf = fmaxf(0.f, su_temp - sumax);
                float qu_out = fmaf(qu_in, psi, ovf);
                float pwp = 0.8f * sumax;
                float ktheta = (su <= pwp) ? su * inv_sumax : 1.f;
                float ret = bx.z * ktheta;
                su = fmaxf(0.f, su - ret);
                float qi_in = qu_out * perc;
                si += qi_in;
                float qi_out = si * rki;
                si -= qi_out;
                float qb_in = qu_out - qi_in;
                sb += qb_in;
                float qb_out = sb * rkb;
                sb -= qb_out;

                float q = row_sum16(qf_out + qi_out + qb_out) * 0.0625f;
                if (m == 0) op[c * CS + tl] = q;
            }
        } else if (c + 1 < NCHUNK) {
            produce(c + 1, (c + 1) & 1);
        }
        __syncthreads();
    }
}

extern "C" void kernel_launch(void* const* d_in, const int* in_sizes, int n_in,
                              void* d_out, int out_size, void* d_ws, size_t ws_size,
                              hipStream_t stream) {
    const float* xc = (const float*)d_in[0];   // [256,1460,3]
    const float* lo = (const float*)d_in[1];   // [256,1460,128]
    float* out = (float*)d_out;                // [256,1460,1]

    const size_t R2_BYTES = (size_t)NREC * 16;  // 95,682,560
    const size_t V_BYTES  = (size_t)NBT * 16;   //  5,980,160

    if (ws_size >= R2_BYTES + V_BYTES) {
        uint4* R2 = (uint4*)d_ws;
        float* V  = (float*)((char*)d_ws + R2_BYTES);
        shm_param_kernel<<<dim3(NREC / 256), dim3(256), 0, stream>>>(xc, lo, R2, V);
        shm_serial_kernel<<<dim3(64), dim3(192), 0, stream>>>(
            (const char*)R2, (const char*)V, out);
    } else {
        shm_pc_kernel<<<dim3(64), dim3(256), 0, stream>>>(xc, lo, out);
    }
}